// Round 10
// baseline (627.187 us; speedup 1.0000x reference)
//
#include <hip/hip_runtime.h>
#include <hip/hip_cooperative_groups.h>
#include <cstdint>
#include <cstddef>

namespace cg = cooperative_groups;

typedef __bf16 bf16_t;
typedef __bf16 bf16x8 __attribute__((ext_vector_type(8)));
typedef float  f32x4  __attribute__((ext_vector_type(4)));

#define D_MODEL 768
#define D_INNER 1536
#define D_STATE 16
#define DT_RANK 48
#define NB      2
#define SEQ     2048
#define NTOK    (NB*SEQ)   // 4096
#define XPROJ_N (DT_RANK + 2*D_STATE)  // 80
#define LC      32
#define NCHUNK  (SEQ/LC)   // 64
#define XP_KS   4          // x_proj split-K factor
#define XP_KC   (D_INNER/XP_KS)  // 384

#define N_INW (2*D_INNER*D_MODEL)   // 2359296
#define N_XPW (XPROJ_N*D_INNER)     // 122880
#define N_DTW (D_INNER*DT_RANK)     // 73728
#define N_OPW (D_MODEL*D_INNER)     // 1179648
#define N_CVT (N_INW+N_XPW+N_DTW+N_OPW)       // 3735552
#define CVT_BLOCKS (N_CVT/1024)               // 3648 (256 thr x 4 elem)
#define ZERO_BLOCKS ((NTOK*XPROJ_N)/1024)     // 320 (proj_f32 zeroing)

// async global->LDS, 16B per lane; lds base must be wave-uniform, HW adds lane*16
typedef __attribute__((address_space(1))) void gvoid_t;
typedef __attribute__((address_space(3))) void lvoid_t;
__device__ __forceinline__ void g2lds16(const bf16_t* g, bf16_t* l) {
    __builtin_amdgcn_global_load_lds((gvoid_t*)g, (lvoid_t*)l, 16, 0, 0);
}

// ---------------- prep: weight cvt (vec4) + RMSNorm + proj_f32 zero ---------
__global__ __launch_bounds__(256)
void prep_kernel(const float* __restrict__ in_proj_w, bf16_t* __restrict__ w_in,
                 const float* __restrict__ x_proj_w,  bf16_t* __restrict__ w_xp,
                 const float* __restrict__ dt_proj_w, bf16_t* __restrict__ w_dt,
                 const float* __restrict__ out_proj_w,bf16_t* __restrict__ w_op,
                 const float* __restrict__ x, const float* __restrict__ norm_w,
                 bf16_t* __restrict__ h, float* __restrict__ projf) {
    const int blk = blockIdx.x;
    const int tid = threadIdx.x;
    if (blk < CVT_BLOCKS) {
        int off = (blk * 256 + tid) * 4;
        const float* s; bf16_t* d;
        if (off < N_INW) { s = in_proj_w + off; d = w_in + off; }
        else if ((off -= N_INW) < N_XPW) { s = x_proj_w + off; d = w_xp + off; }
        else if ((off -= N_XPW) < N_DTW) { s = dt_proj_w + off; d = w_dt + off; }
        else { off -= N_DTW; s = out_proj_w + off; d = w_op + off; }
        float4 v = *(const float4*)s;
        d[0] = (bf16_t)v.x; d[1] = (bf16_t)v.y;
        d[2] = (bf16_t)v.z; d[3] = (bf16_t)v.w;
        return;
    }
    if (blk >= CVT_BLOCKS + NTOK) {   // zero proj_f32
        int i = (blk - CVT_BLOCKS - NTOK) * 1024 + tid * 4;
        float4 z = {0.f, 0.f, 0.f, 0.f};
        *(float4*)&projf[i] = z;
        return;
    }
    // RMSNorm: one block per token
    int t = blk - CVT_BLOCKS;
    const float* xr = x + (size_t)t * D_MODEL;
    float v[3];
    float ss = 0.f;
#pragma unroll
    for (int i = 0; i < 3; i++) { v[i] = xr[tid + 256*i]; ss += v[i]*v[i]; }
#pragma unroll
    for (int off = 32; off >= 1; off >>= 1) ss += __shfl_down(ss, off);
    __shared__ float red[4];
    int lane = tid & 63, wv = tid >> 6;
    if (lane == 0) red[wv] = ss;
    __syncthreads();
    float tot = red[0] + red[1] + red[2] + red[3];
    float r = rsqrtf(tot * (1.f/(float)D_MODEL) + 1e-5f);
#pragma unroll
    for (int i = 0; i < 3; i++)
        h[(size_t)t*D_MODEL + tid + 256*i] = (bf16_t)(v[i] * r * norm_w[tid + 256*i]);
}

// ---------------- in_proj: 128x128 NT GEMM, dbuf single-barrier, swizzled ----
__global__ __launch_bounds__(256)
void gemm_nt128(const bf16_t* __restrict__ A, int lda,
                const bf16_t* __restrict__ B, int ldb,
                bf16_t* __restrict__ C, int ldc, int K) {
    __shared__ __align__(16) bf16_t As[2][128*32];
    __shared__ __align__(16) bf16_t Bs[2][128*32];
    const int tid = threadIdx.x;
    const int wave = tid >> 6, lane = tid & 63;
    const int quad = lane >> 4, l16 = lane & 15;
    const int m0 = blockIdx.x * 128, n0 = blockIdx.y * 128;
    const int wr = (wave >> 1) * 64, wc = (wave & 1) * 64;

    const int s0 = tid, s1 = tid + 256;
    const int r0 = s0 >> 2, q0 = ((s0 & 3) ^ ((r0 >> 1) & 3)) << 3;
    const int r1 = s1 >> 2, q1 = ((s1 & 3) ^ ((r1 >> 1) & 3)) << 3;

    const bf16_t* Ar0 = A + (size_t)(m0 + r0)*lda + q0;
    const bf16_t* Ar1 = A + (size_t)(m0 + r1)*lda + q1;
    const bf16_t* Br0 = B + (size_t)(n0 + r0)*ldb + q0;
    const bf16_t* Br1 = B + (size_t)(n0 + r1)*ldb + q1;

    f32x4 acc[4][4] = {};
    const int nit = K >> 5;

    g2lds16(Ar0, &As[0][wave*512]);
    g2lds16(Ar1, &As[0][wave*512 + 2048]);
    g2lds16(Br0, &Bs[0][wave*512]);
    g2lds16(Br1, &Bs[0][wave*512 + 2048]);

    for (int it = 0; it < nit; it++) {
        __syncthreads();
        if (it + 1 < nit) {
            int k = (it + 1) << 5;
            int nb = (it + 1) & 1;
            g2lds16(Ar0 + k, &As[nb][wave*512]);
            g2lds16(Ar1 + k, &As[nb][wave*512 + 2048]);
            g2lds16(Br0 + k, &Bs[nb][wave*512]);
            g2lds16(Br1 + k, &Bs[nb][wave*512 + 2048]);
        }
        const int buf = it & 1;
        bf16x8 af[4], bfr[4];
#pragma unroll
        for (int i = 0; i < 4; i++) {
            int rr = wr + i*16 + l16;
            af[i] = *(const bf16x8*)&As[buf][rr*32 + ((quad ^ ((rr >> 1) & 3)) << 3)];
        }
#pragma unroll
        for (int j = 0; j < 4; j++) {
            int rr = wc + j*16 + l16;
            bfr[j] = *(const bf16x8*)&Bs[buf][rr*32 + ((quad ^ ((rr >> 1) & 3)) << 3)];
        }
#pragma unroll
        for (int i = 0; i < 4; i++)
#pragma unroll
            for (int j = 0; j < 4; j++)
                acc[i][j] = __builtin_amdgcn_mfma_f32_16x16x32_bf16(af[i], bfr[j], acc[i][j], 0, 0, 0);
    }

#pragma unroll
    for (int i = 0; i < 4; i++)
#pragma unroll
        for (int j = 0; j < 4; j++) {
            int n = n0 + wc + j*16 + l16;
#pragma unroll
            for (int rr = 0; rr < 4; rr++) {
                int m = m0 + wr + i*16 + quad*4 + rr;
                C[(size_t)m * ldc + n] = (bf16_t)acc[i][j][rr];
            }
        }
}

// ---------------- out_proj: 128x64 NT GEMM, dbuf, + residual epilogue -------
__global__ __launch_bounds__(256)
void gemm_op(const bf16_t* __restrict__ A, const bf16_t* __restrict__ B,
             float* __restrict__ C, const float* __restrict__ resid,
             float* __restrict__ resid_out) {
    __shared__ __align__(16) bf16_t As[2][128*32];
    __shared__ __align__(16) bf16_t Bs[2][64*32];
    const int tid = threadIdx.x;
    const int wave = tid >> 6, lane = tid & 63;
    const int quad = lane >> 4, l16 = lane & 15;
    const int m0 = blockIdx.x * 128, n0 = blockIdx.y * 64;
    const int wr = (wave >> 1) * 64, wc = (wave & 1) * 32;

    const int s0 = tid, s1 = tid + 256;
    const int r0 = s0 >> 2, q0 = ((s0 & 3) ^ ((r0 >> 1) & 3)) << 3;
    const int r1 = s1 >> 2, q1 = ((s1 & 3) ^ ((r1 >> 1) & 3)) << 3;
    const int rB = tid >> 2, qB = (((tid & 3) ^ ((rB >> 1) & 3)) << 3);

    const bf16_t* Ar0 = A + (size_t)(m0 + r0)*D_INNER + q0;
    const bf16_t* Ar1 = A + (size_t)(m0 + r1)*D_INNER + q1;
    const bf16_t* Brp = B + (size_t)(n0 + rB)*D_INNER + qB;

    f32x4 acc[4][2] = {};
    const int nit = D_INNER >> 5;   // 48

    g2lds16(Ar0, &As[0][wave*512]);
    g2lds16(Ar1, &As[0][wave*512 + 2048]);
    g2lds16(Brp, &Bs[0][wave*512]);

    for (int it = 0; it < nit; it++) {
        __syncthreads();
        if (it + 1 < nit) {
            int k = (it + 1) << 5;
            int nb = (it + 1) & 1;
            g2lds16(Ar0 + k, &As[nb][wave*512]);
            g2lds16(Ar1 + k, &As[nb][wave*512 + 2048]);
            g2lds16(Brp + k, &Bs[nb][wave*512]);
        }
        const int buf = it & 1;
        bf16x8 af[4], bfr[2];
#pragma unroll
        for (int i = 0; i < 4; i++) {
            int rr = wr + i*16 + l16;
            af[i] = *(const bf16x8*)&As[buf][rr*32 + ((quad ^ ((rr >> 1) & 3)) << 3)];
        }
#pragma unroll
        for (int j = 0; j < 2; j++) {
            int rr = wc + j*16 + l16;
            bfr[j] = *(const bf16x8*)&Bs[buf][rr*32 + ((quad ^ ((rr >> 1) & 3)) << 3)];
        }
#pragma unroll
        for (int i = 0; i < 4; i++)
#pragma unroll
            for (int j = 0; j < 2; j++)
                acc[i][j] = __builtin_amdgcn_mfma_f32_16x16x32_bf16(af[i], bfr[j], acc[i][j], 0, 0, 0);
    }

#pragma unroll
    for (int i = 0; i < 4; i++)
#pragma unroll
        for (int j = 0; j < 2; j++) {
            int n = n0 + wc + j*16 + l16;
#pragma unroll
            for (int rr = 0; rr < 4; rr++) {
                int m = m0 + wr + i*16 + quad*4 + rr;
                size_t idx = (size_t)m * D_MODEL + n;
                float rx = resid[idx];
                C[idx] = acc[i][j][rr] + rx;
                resid_out[idx] = rx;
            }
        }
}

// ---------------- x_proj: 64x64 tile, split-K x4, atomic fp32 accumulate ----
__global__ __launch_bounds__(256)
void gemm_xp(const bf16_t* __restrict__ A, const bf16_t* __restrict__ B,
             float* __restrict__ projf) {
    __shared__ __align__(16) bf16_t As[64*32];
    __shared__ __align__(16) bf16_t Bs[64*32];
    const int tid = threadIdx.x;
    const int m0 = blockIdx.x * 64, n0 = blockIdx.y * 64, kbase = blockIdx.z * XP_KC;
    const int r  = tid >> 2, p8 = (tid & 3) << 3;
    const int q8 = (((tid & 3) ^ ((r >> 1) & 3)) << 3);
    const int wave = tid >> 6, lane = tid & 63;
    const int quad = lane >> 4, l16 = lane & 15;

    f32x4 acc[4] = {{0.f,0.f,0.f,0.f},{0.f,0.f,0.f,0.f},
                    {0.f,0.f,0.f,0.f},{0.f,0.f,0.f,0.f}};

    for (int k0 = 0; k0 < XP_KC; k0 += 32) {
        int gk = kbase + k0 + q8;
        uint4 va = *(const uint4*)(A + (size_t)(m0 + r) * D_INNER + gk);
        *(uint4*)&As[r*32 + p8] = va;
        uint4 vb = {0u,0u,0u,0u};
        int nr = n0 + r;
        if (nr < XPROJ_N)
            vb = *(const uint4*)(B + (size_t)nr * D_INNER + gk);
        *(uint4*)&Bs[r*32 + p8] = vb;

        __syncthreads();
        int ra = wave*16 + l16;
        bf16x8 af = *(const bf16x8*)&As[ra*32 + ((quad ^ ((ra >> 1) & 3)) << 3)];
#pragma unroll
        for (int nt = 0; nt < 4; nt++) {
            int rb = nt*16 + l16;
            bf16x8 bfg = *(const bf16x8*)&Bs[rb*32 + ((quad ^ ((rb >> 1) & 3)) << 3)];
            acc[nt] = __builtin_amdgcn_mfma_f32_16x16x32_bf16(af, bfg, acc[nt], 0, 0, 0);
        }
        __syncthreads();
    }

#pragma unroll
    for (int nt = 0; nt < 4; nt++) {
        int n = n0 + nt*16 + l16;
        if (n >= XPROJ_N) continue;
#pragma unroll
        for (int rr = 0; rr < 4; rr++) {
            int m = m0 + wave*16 + quad*4 + rr;
            atomicAdd(&projf[(size_t)m * XPROJ_N + n], acc[nt][rr]);
        }
    }
}

// ---------------- dt_proj: 64x64 tile, K=48, A from fp32 proj ---------------
__global__ __launch_bounds__(256)
void gemm_dt(const float* __restrict__ projf, const bf16_t* __restrict__ B,
             bf16_t* __restrict__ C, const float* __restrict__ bias) {
    __shared__ __align__(16) bf16_t As[64*32];
    __shared__ __align__(16) bf16_t Bs[64*32];
    const int tid = threadIdx.x;
    const int m0 = blockIdx.x * 64, n0 = blockIdx.y * 64;
    const int r  = tid >> 2, p8 = (tid & 3) << 3;
    const int q8 = (((tid & 3) ^ ((r >> 1) & 3)) << 3);
    const int wave = tid >> 6, lane = tid & 63;
    const int quad = lane >> 4, l16 = lane & 15;

    f32x4 acc[4] = {{0.f,0.f,0.f,0.f},{0.f,0.f,0.f,0.f},
                    {0.f,0.f,0.f,0.f},{0.f,0.f,0.f,0.f}};

    for (int k0 = 0; k0 < DT_RANK; k0 += 32) {
        int gk = k0 + q8;
        bf16x8 av = {};
        if (gk + 8 <= DT_RANK) {
            const float* ap = projf + (size_t)(m0 + r) * XPROJ_N + gk;
            float4 f0 = *(const float4*)ap;
            float4 f1 = *(const float4*)(ap + 4);
            av[0]=(bf16_t)f0.x; av[1]=(bf16_t)f0.y; av[2]=(bf16_t)f0.z; av[3]=(bf16_t)f0.w;
            av[4]=(bf16_t)f1.x; av[5]=(bf16_t)f1.y; av[6]=(bf16_t)f1.z; av[7]=(bf16_t)f1.w;
        }
        *(bf16x8*)&As[r*32 + p8] = av;
        uint4 vb = {0u,0u,0u,0u};
        if (gk + 8 <= DT_RANK)
            vb = *(const uint4*)(B + (size_t)(n0 + r) * DT_RANK + gk);
        *(uint4*)&Bs[r*32 + p8] = vb;

        __syncthreads();
        int ra = wave*16 + l16;
        bf16x8 af = *(const bf16x8*)&As[ra*32 + ((quad ^ ((ra >> 1) & 3)) << 3)];
#pragma unroll
        for (int nt = 0; nt < 4; nt++) {
            int rb = nt*16 + l16;
            bf16x8 bfg = *(const bf16x8*)&Bs[rb*32 + ((quad ^ ((rb >> 1) & 3)) << 3)];
            acc[nt] = __builtin_amdgcn_mfma_f32_16x16x32_bf16(af, bfg, acc[nt], 0, 0, 0);
        }
        __syncthreads();
    }

#pragma unroll
    for (int nt = 0; nt < 4; nt++) {
        int n = n0 + nt*16 + l16;
#pragma unroll
        for (int rr = 0; rr < 4; rr++) {
            int m = m0 + wave*16 + quad*4 + rr;
            float u = acc[nt][rr] + bias[n];
            float sp = (u > 20.f) ? u : log1pf(__expf(u));
            C[(size_t)m * D_INNER + n] = (bf16_t)sp;
        }
    }
}

// ---------------- causal depthwise conv(4) + SiLU, 8 ch/thread vectorized ---
__global__ __launch_bounds__(192)
void conv_silu_kernel(const bf16_t* __restrict__ xz,
                      const float* __restrict__ cw,
                      const float* __restrict__ cb,
                      bf16_t* __restrict__ xc) {
    const int t = blockIdx.x;
    const int l = t & (SEQ - 1);
    const int d = threadIdx.x * 8;       // 192*8 = 1536

    float cwf[32];
#pragma unroll
    for (int q = 0; q < 8; q++)
        *(float4*)&cwf[q*4] = *(const float4*)&cw[d*4 + q*4];

    float acc[8];
    {
        float4 c0 = *(const float4*)&cb[d];
        float4 c1 = *(const float4*)&cb[d+4];
        acc[0]=c0.x; acc[1]=c0.y; acc[2]=c0.z; acc[3]=c0.w;
        acc[4]=c1.x; acc[5]=c1.y; acc[6]=c1.z; acc[7]=c1.w;
    }
#pragma unroll
    for (int k = 0; k < 4; k++) {
        if (l - 3 + k >= 0) {
            bf16x8 v = *(const bf16x8*)&xz[(size_t)(t - 3 + k) * (2*D_INNER) + d];
#pragma unroll
            for (int i = 0; i < 8; i++)
                acc[i] += (float)v[i] * cwf[i*4 + k];
        }
    }
    bf16x8 o;
#pragma unroll
    for (int i = 0; i < 8; i++) {
        float s = acc[i] / (1.f + __expf(-acc[i]));
        o[i] = (bf16_t)s;
    }
    *(bf16x8*)&xc[(size_t)t * D_INNER + d] = o;
}

// ---------------- fused cooperative selective scan --------------------------
// Phase A: per-(b,c,d) local recurrence from 0; keep (delta,xc) packed in
//          VGPRs and B/C rows in LDS. Publish S[16] + sum(dv).
// Phase B: 49152 chain-threads combine the 64 chunks serially, storing each
//          chunk's initial state in-place.
// Phase C: re-run recurrence from the initial state using the cached regs;
//          emit y = (C·h + D*xc) * silu(z).
__global__ __launch_bounds__(256)
void scan_fused(const bf16_t* __restrict__ delta,
                const bf16_t* __restrict__ xc,
                const float* __restrict__ projf,
                const bf16_t* __restrict__ xz,
                const float* __restrict__ A_log,
                const float* __restrict__ Dw,
                float* __restrict__ Sbuf,    // [b][c][d][n]
                float* __restrict__ sdvbuf,  // [b][c][d]
                bf16_t* __restrict__ y) {
    cg::grid_group grid = cg::this_grid();
    const int tid = threadIdx.x;
    const int d = blockIdx.x * 256 + tid;
    const int c = blockIdx.y;
    const int b = blockIdx.z;
    __shared__ float Bs[LC][D_STATE];
    __shared__ float Cs[LC][D_STATE];
    for (int i = tid; i < LC*D_STATE; i += 256) {
        int l = i >> 4, n = i & 15;
        size_t t = (size_t)b*SEQ + (size_t)c*LC + l;
        Bs[l][n] = projf[t*XPROJ_N + DT_RANK + n];
        Cs[l][n] = projf[t*XPROJ_N + DT_RANK + D_STATE + n];
    }
    float Av2[D_STATE];
#pragma unroll
    for (int n = 0; n < D_STATE; n++)
        Av2[n] = -__expf(A_log[d*D_STATE + n]) * 1.44269504f;
    __syncthreads();

    // ---- phase A ----
    const unsigned short* dpu = (const unsigned short*)delta;
    const unsigned short* xpu = (const unsigned short*)xc;
    const size_t tbase = (size_t)b*SEQ + (size_t)c*LC;
    unsigned pack[LC];
    float s[D_STATE];
#pragma unroll
    for (int n = 0; n < D_STATE; n++) s[n] = 0.f;
    float sdv = 0.f;
    for (int l = 0; l < LC; l++) {
        size_t t = tbase + l;
        unsigned dvu = dpu[t*D_INNER + d];
        unsigned xcu = xpu[t*D_INNER + d];
        pack[l] = (xcu << 16) | dvu;
        float dv  = __uint_as_float(dvu << 16);
        float xcf = __uint_as_float(pack[l] & 0xFFFF0000u);
        float dx = dv * xcf;
        sdv += dv;
#pragma unroll
        for (int n = 0; n < D_STATE; n++) {
            float a = __builtin_amdgcn_exp2f(dv * Av2[n]);
            s[n] = a * s[n] + dx * Bs[l][n];
        }
    }
    const size_t base = (((size_t)b*NCHUNK + c)*D_INNER + d)*D_STATE;
#pragma unroll
    for (int n = 0; n < D_STATE; n++) Sbuf[base + n] = s[n];
    sdvbuf[((size_t)b*NCHUNK + c)*D_INNER + d] = sdv;

    __threadfence();
    grid.sync();

    // ---- phase B: chunk combine, one thread per (b,d,n) chain ----
    {
        unsigned rank = (unsigned)grid.thread_rank();
        if (rank < (unsigned)(NB * D_INNER * D_STATE)) {
            int b2 = rank / (D_INNER * D_STATE);
            int dn = rank - b2 * (D_INNER * D_STATE);
            int d2 = dn >> 4;
            float Avc = -__expf(A_log[dn]) * 1.44269504f;
            float H = 0.f;
            for (int c2 = 0; c2 < NCHUNK; c2++) {
                size_t idx = ((size_t)b2*NCHUNK + c2)*D_INNER*D_STATE + dn;
                float S  = Sbuf[idx];
                float sv = sdvbuf[((size_t)b2*NCHUNK + c2)*D_INNER + d2];
                Sbuf[idx] = H;                 // initial state for chunk c2
                H = __builtin_amdgcn_exp2f(Avc * sv) * H + S;
            }
        }
    }

    __threadfence();
    grid.sync();

    // ---- phase C ----
#pragma unroll
    for (int n = 0; n < D_STATE; n++) s[n] = Sbuf[base + n];
    const float Dv = Dw[d];
    for (int l = 0; l < LC; l++) {
        size_t t = tbase + l;
        float dv  = __uint_as_float(pack[l] << 16);
        float xcf = __uint_as_float(pack[l] & 0xFFFF0000u);
        float dx = dv * xcf;
        float acc = 0.f;
#pragma unroll
        for (int n = 0; n < D_STATE; n++) {
            float a = __builtin_amdgcn_exp2f(dv * Av2[n]);
            s[n] = a * s[n] + dx * Bs[l][n];
            acc += s[n] * Cs[l][n];
        }
        float zf = (float)xz[t*(2*D_INNER) + D_INNER + d];
        float g = zf / (1.f + __expf(-zf));
        y[t*D_INNER + d] = (bf16_t)((acc + xcf * Dv) * g);
    }
}

extern "C" void kernel_launch(void* const* d_in, const int* in_sizes, int n_in,
                              void* d_out, int out_size, void* d_ws, size_t ws_size,
                              hipStream_t stream) {
    const float* x          = (const float*)d_in[0];
    const float* norm_w     = (const float*)d_in[1];
    const float* in_proj_w  = (const float*)d_in[2];
    const float* conv_w     = (const float*)d_in[3];
    const float* conv_b     = (const float*)d_in[4];
    const float* x_proj_w   = (const float*)d_in[5];
    const float* dt_proj_w  = (const float*)d_in[6];
    const float* dt_proj_b  = (const float*)d_in[7];
    const float* A_log      = (const float*)d_in[8];
    const float* Dw         = (const float*)d_in[9];
    const float* out_proj_w = (const float*)d_in[10];

    float* out0 = (float*)d_out;                       // x + out_proj(y)
    float* out1 = out0 + (size_t)NTOK * D_MODEL;       // residual copy

    const size_t n_chunkst = (size_t)NB*NCHUNK*D_INNER*D_STATE;

    char* ws = (char*)d_ws;
    bf16_t* w_in  = (bf16_t*)ws;  ws += (size_t)N_INW * sizeof(bf16_t);
    bf16_t* w_xp  = (bf16_t*)ws;  ws += (size_t)N_XPW * sizeof(bf16_t);
    bf16_t* w_dt  = (bf16_t*)ws;  ws += (size_t)N_DTW * sizeof(bf16_t);
    bf16_t* w_op  = (bf16_t*)ws;  ws += (size_t)N_OPW * sizeof(bf16_t);
    bf16_t* h     = (bf16_t*)ws;  ws += (size_t)NTOK * D_MODEL   * sizeof(bf16_t);
    bf16_t* xz    = (bf16_t*)ws;  ws += (size_t)NTOK * 2*D_INNER * sizeof(bf16_t);
    bf16_t* xc    = (bf16_t*)ws;  ws += (size_t)NTOK * D_INNER   * sizeof(bf16_t);
    float*  projf = (float*)ws;   ws += (size_t)NTOK * XPROJ_N   * sizeof(float);
    bf16_t* delta = (bf16_t*)ws;  ws += (size_t)NTOK * D_INNER   * sizeof(bf16_t);
    bf16_t* y     = (bf16_t*)ws;  ws += (size_t)NTOK * D_INNER   * sizeof(bf16_t);
    float*  Sbuf  = (float*)ws;   ws += n_chunkst * sizeof(float);
    float*  sdvb  = (float*)ws;   ws += (size_t)NB*NCHUNK*D_INNER * sizeof(float);

    // 0+1) weight cvt + RMSNorm + proj_f32 zero, one launch
    prep_kernel<<<CVT_BLOCKS + NTOK + ZERO_BLOCKS, 256, 0, stream>>>(
        in_proj_w, w_in, x_proj_w, w_xp, dt_proj_w, w_dt, out_proj_w, w_op,
        x, norm_w, h, projf);
    // 2) in_proj (dbuf 128-tile)
    gemm_nt128<<<dim3(NTOK/128, (2*D_INNER)/128), 256, 0, stream>>>(
        h, D_MODEL, w_in, D_MODEL, xz, 2*D_INNER, D_MODEL);
    // 3) conv + SiLU
    conv_silu_kernel<<<NTOK, 192, 0, stream>>>(xz, conv_w, conv_b, xc);
    // 4) x_proj split-K x4, atomic fp32 accumulate into projf
    gemm_xp<<<dim3(NTOK/64, 2, XP_KS), 256, 0, stream>>>(xc, w_xp, projf);
    // 5) dt_proj + softplus (A staged from fp32 projf)
    gemm_dt<<<dim3(NTOK/64, D_INNER/64), 256, 0, stream>>>(projf, w_dt, delta, dt_proj_b);
    // 6) fused cooperative selective scan (768 blocks = 3/CU co-resident)
    {
        const bf16_t* a0 = delta; const bf16_t* a1 = xc; const float* a2 = projf;
        const bf16_t* a3 = xz; const float* a4 = A_log; const float* a5 = Dw;
        float* a6 = Sbuf; float* a7 = sdvb; bf16_t* a8 = y;
        void* args[] = {&a0, &a1, &a2, &a3, &a4, &a5, &a6, &a7, &a8};
        hipLaunchCooperativeKernel((void*)scan_fused,
                                   dim3(D_INNER/256, NCHUNK, NB), dim3(256),
                                   args, 0, stream);
    }
    // 7) out_proj 128x64 dbuf + residual epilogue
    gemm_op<<<dim3(NTOK/128, D_MODEL/64), 256, 0, stream>>>(
        y, w_op, out0, x, out1);
}

// Round 11
// 292.374 us; speedup vs baseline: 2.1451x; 2.1451x over previous
//
#include <hip/hip_runtime.h>
#include <cstdint>
#include <cstddef>

typedef __bf16 bf16_t;
typedef __bf16 bf16x8 __attribute__((ext_vector_type(8)));
typedef float  f32x4  __attribute__((ext_vector_type(4)));

#define D_MODEL 768
#define D_INNER 1536
#define D_STATE 16
#define DT_RANK 48
#define NB      2
#define SEQ     2048
#define NTOK    (NB*SEQ)   // 4096
#define XPROJ_N (DT_RANK + 2*D_STATE)  // 80
#define LC      32
#define NCHUNK  (SEQ/LC)   // 64
#define XP_KS   4          // x_proj split-K factor
#define XP_KC   (D_INNER/XP_KS)  // 384

#define N_INW (2*D_INNER*D_MODEL)   // 2359296
#define N_XPW (XPROJ_N*D_INNER)     // 122880
#define N_DTW (D_INNER*DT_RANK)     // 73728
#define N_OPW (D_MODEL*D_INNER)     // 1179648
#define N_CVT (N_INW+N_XPW+N_DTW+N_OPW)       // 3735552
#define CVT_BLOCKS (N_CVT/1024)               // 3648 (256 thr x 4 elem)
#define ZERO_BLOCKS ((NTOK*XPROJ_N)/1024)     // 320 (proj_f32 zeroing)

// async global->LDS, 16B per lane; lds base must be wave-uniform, HW adds lane*16
typedef __attribute__((address_space(1))) void gvoid_t;
typedef __attribute__((address_space(3))) void lvoid_t;
__device__ __forceinline__ void g2lds16(const bf16_t* g, bf16_t* l) {
    __builtin_amdgcn_global_load_lds((gvoid_t*)g, (lvoid_t*)l, 16, 0, 0);
}

// ---------------- prep: weight cvt (vec4) + RMSNorm + proj_f32 zero ---------
__global__ __launch_bounds__(256)
void prep_kernel(const float* __restrict__ in_proj_w, bf16_t* __restrict__ w_in,
                 const float* __restrict__ x_proj_w,  bf16_t* __restrict__ w_xp,
                 const float* __restrict__ dt_proj_w, bf16_t* __restrict__ w_dt,
                 const float* __restrict__ out_proj_w,bf16_t* __restrict__ w_op,
                 const float* __restrict__ x, const float* __restrict__ norm_w,
                 bf16_t* __restrict__ h, float* __restrict__ projf) {
    const int blk = blockIdx.x;
    const int tid = threadIdx.x;
    if (blk < CVT_BLOCKS) {
        int off = (blk * 256 + tid) * 4;
        const float* s; bf16_t* d;
        if (off < N_INW) { s = in_proj_w + off; d = w_in + off; }
        else if ((off -= N_INW) < N_XPW) { s = x_proj_w + off; d = w_xp + off; }
        else if ((off -= N_XPW) < N_DTW) { s = dt_proj_w + off; d = w_dt + off; }
        else { off -= N_DTW; s = out_proj_w + off; d = w_op + off; }
        float4 v = *(const float4*)s;
        d[0] = (bf16_t)v.x; d[1] = (bf16_t)v.y;
        d[2] = (bf16_t)v.z; d[3] = (bf16_t)v.w;
        return;
    }
    if (blk >= CVT_BLOCKS + NTOK) {   // zero proj_f32
        int i = (blk - CVT_BLOCKS - NTOK) * 1024 + tid * 4;
        float4 z = {0.f, 0.f, 0.f, 0.f};
        *(float4*)&projf[i] = z;
        return;
    }
    // RMSNorm: one block per token
    int t = blk - CVT_BLOCKS;
    const float* xr = x + (size_t)t * D_MODEL;
    float v[3];
    float ss = 0.f;
#pragma unroll
    for (int i = 0; i < 3; i++) { v[i] = xr[tid + 256*i]; ss += v[i]*v[i]; }
#pragma unroll
    for (int off = 32; off >= 1; off >>= 1) ss += __shfl_down(ss, off);
    __shared__ float red[4];
    int lane = tid & 63, wv = tid >> 6;
    if (lane == 0) red[wv] = ss;
    __syncthreads();
    float tot = red[0] + red[1] + red[2] + red[3];
    float r = rsqrtf(tot * (1.f/(float)D_MODEL) + 1e-5f);
#pragma unroll
    for (int i = 0; i < 3; i++)
        h[(size_t)t*D_MODEL + tid + 256*i] = (bf16_t)(v[i] * r * norm_w[tid + 256*i]);
}

// ---------------- in_proj: 128x128 NT GEMM, dbuf single-barrier, swizzled ----
__global__ __launch_bounds__(256)
void gemm_nt128(const bf16_t* __restrict__ A, int lda,
                const bf16_t* __restrict__ B, int ldb,
                bf16_t* __restrict__ C, int ldc, int K) {
    __shared__ __align__(16) bf16_t As[2][128*32];
    __shared__ __align__(16) bf16_t Bs[2][128*32];
    const int tid = threadIdx.x;
    const int wave = tid >> 6, lane = tid & 63;
    const int quad = lane >> 4, l16 = lane & 15;
    const int m0 = blockIdx.x * 128, n0 = blockIdx.y * 128;
    const int wr = (wave >> 1) * 64, wc = (wave & 1) * 64;

    const int s0 = tid, s1 = tid + 256;
    const int r0 = s0 >> 2, q0 = ((s0 & 3) ^ ((r0 >> 1) & 3)) << 3;
    const int r1 = s1 >> 2, q1 = ((s1 & 3) ^ ((r1 >> 1) & 3)) << 3;

    const bf16_t* Ar0 = A + (size_t)(m0 + r0)*lda + q0;
    const bf16_t* Ar1 = A + (size_t)(m0 + r1)*lda + q1;
    const bf16_t* Br0 = B + (size_t)(n0 + r0)*ldb + q0;
    const bf16_t* Br1 = B + (size_t)(n0 + r1)*ldb + q1;

    f32x4 acc[4][4] = {};
    const int nit = K >> 5;

    g2lds16(Ar0, &As[0][wave*512]);
    g2lds16(Ar1, &As[0][wave*512 + 2048]);
    g2lds16(Br0, &Bs[0][wave*512]);
    g2lds16(Br1, &Bs[0][wave*512 + 2048]);

    for (int it = 0; it < nit; it++) {
        __syncthreads();
        if (it + 1 < nit) {
            int k = (it + 1) << 5;
            int nb = (it + 1) & 1;
            g2lds16(Ar0 + k, &As[nb][wave*512]);
            g2lds16(Ar1 + k, &As[nb][wave*512 + 2048]);
            g2lds16(Br0 + k, &Bs[nb][wave*512]);
            g2lds16(Br1 + k, &Bs[nb][wave*512 + 2048]);
        }
        const int buf = it & 1;
        bf16x8 af[4], bfr[4];
#pragma unroll
        for (int i = 0; i < 4; i++) {
            int rr = wr + i*16 + l16;
            af[i] = *(const bf16x8*)&As[buf][rr*32 + ((quad ^ ((rr >> 1) & 3)) << 3)];
        }
#pragma unroll
        for (int j = 0; j < 4; j++) {
            int rr = wc + j*16 + l16;
            bfr[j] = *(const bf16x8*)&Bs[buf][rr*32 + ((quad ^ ((rr >> 1) & 3)) << 3)];
        }
#pragma unroll
        for (int i = 0; i < 4; i++)
#pragma unroll
            for (int j = 0; j < 4; j++)
                acc[i][j] = __builtin_amdgcn_mfma_f32_16x16x32_bf16(af[i], bfr[j], acc[i][j], 0, 0, 0);
    }

#pragma unroll
    for (int i = 0; i < 4; i++)
#pragma unroll
        for (int j = 0; j < 4; j++) {
            int n = n0 + wc + j*16 + l16;
#pragma unroll
            for (int rr = 0; rr < 4; rr++) {
                int m = m0 + wr + i*16 + quad*4 + rr;
                C[(size_t)m * ldc + n] = (bf16_t)acc[i][j][rr];
            }
        }
}

// ---------------- out_proj: 128x64 NT GEMM, dbuf, + residual epilogue -------
__global__ __launch_bounds__(256)
void gemm_op(const bf16_t* __restrict__ A, const bf16_t* __restrict__ B,
             float* __restrict__ C, const float* __restrict__ resid,
             float* __restrict__ resid_out) {
    __shared__ __align__(16) bf16_t As[2][128*32];
    __shared__ __align__(16) bf16_t Bs[2][64*32];
    const int tid = threadIdx.x;
    const int wave = tid >> 6, lane = tid & 63;
    const int quad = lane >> 4, l16 = lane & 15;
    const int m0 = blockIdx.x * 128, n0 = blockIdx.y * 64;
    const int wr = (wave >> 1) * 64, wc = (wave & 1) * 32;

    const int s0 = tid, s1 = tid + 256;
    const int r0 = s0 >> 2, q0 = ((s0 & 3) ^ ((r0 >> 1) & 3)) << 3;
    const int r1 = s1 >> 2, q1 = ((s1 & 3) ^ ((r1 >> 1) & 3)) << 3;
    const int rB = tid >> 2, qB = (((tid & 3) ^ ((rB >> 1) & 3)) << 3);

    const bf16_t* Ar0 = A + (size_t)(m0 + r0)*D_INNER + q0;
    const bf16_t* Ar1 = A + (size_t)(m0 + r1)*D_INNER + q1;
    const bf16_t* Brp = B + (size_t)(n0 + rB)*D_INNER + qB;

    f32x4 acc[4][2] = {};
    const int nit = D_INNER >> 5;   // 48

    g2lds16(Ar0, &As[0][wave*512]);
    g2lds16(Ar1, &As[0][wave*512 + 2048]);
    g2lds16(Brp, &Bs[0][wave*512]);

    for (int it = 0; it < nit; it++) {
        __syncthreads();
        if (it + 1 < nit) {
            int k = (it + 1) << 5;
            int nb = (it + 1) & 1;
            g2lds16(Ar0 + k, &As[nb][wave*512]);
            g2lds16(Ar1 + k, &As[nb][wave*512 + 2048]);
            g2lds16(Brp + k, &Bs[nb][wave*512]);
        }
        const int buf = it & 1;
        bf16x8 af[4], bfr[2];
#pragma unroll
        for (int i = 0; i < 4; i++) {
            int rr = wr + i*16 + l16;
            af[i] = *(const bf16x8*)&As[buf][rr*32 + ((quad ^ ((rr >> 1) & 3)) << 3)];
        }
#pragma unroll
        for (int j = 0; j < 2; j++) {
            int rr = wc + j*16 + l16;
            bfr[j] = *(const bf16x8*)&Bs[buf][rr*32 + ((quad ^ ((rr >> 1) & 3)) << 3)];
        }
#pragma unroll
        for (int i = 0; i < 4; i++)
#pragma unroll
            for (int j = 0; j < 2; j++)
                acc[i][j] = __builtin_amdgcn_mfma_f32_16x16x32_bf16(af[i], bfr[j], acc[i][j], 0, 0, 0);
    }

#pragma unroll
    for (int i = 0; i < 4; i++)
#pragma unroll
        for (int j = 0; j < 2; j++) {
            int n = n0 + wc + j*16 + l16;
#pragma unroll
            for (int rr = 0; rr < 4; rr++) {
                int m = m0 + wr + i*16 + quad*4 + rr;
                size_t idx = (size_t)m * D_MODEL + n;
                float rx = resid[idx];
                C[idx] = acc[i][j][rr] + rx;
                resid_out[idx] = rx;
            }
        }
}

// ---------------- x_proj: 64x64 tile, split-K x4, atomic fp32 accumulate ----
__global__ __launch_bounds__(256)
void gemm_xp(const bf16_t* __restrict__ A, const bf16_t* __restrict__ B,
             float* __restrict__ projf) {
    __shared__ __align__(16) bf16_t As[64*32];
    __shared__ __align__(16) bf16_t Bs[64*32];
    const int tid = threadIdx.x;
    const int m0 = blockIdx.x * 64, n0 = blockIdx.y * 64, kbase = blockIdx.z * XP_KC;
    const int r  = tid >> 2, p8 = (tid & 3) << 3;
    const int q8 = (((tid & 3) ^ ((r >> 1) & 3)) << 3);
    const int wave = tid >> 6, lane = tid & 63;
    const int quad = lane >> 4, l16 = lane & 15;

    f32x4 acc[4] = {{0.f,0.f,0.f,0.f},{0.f,0.f,0.f,0.f},
                    {0.f,0.f,0.f,0.f},{0.f,0.f,0.f,0.f}};

    for (int k0 = 0; k0 < XP_KC; k0 += 32) {
        int gk = kbase + k0 + q8;
        uint4 va = *(const uint4*)(A + (size_t)(m0 + r) * D_INNER + gk);
        *(uint4*)&As[r*32 + p8] = va;
        uint4 vb = {0u,0u,0u,0u};
        int nr = n0 + r;
        if (nr < XPROJ_N)
            vb = *(const uint4*)(B + (size_t)nr * D_INNER + gk);
        *(uint4*)&Bs[r*32 + p8] = vb;

        __syncthreads();
        int ra = wave*16 + l16;
        bf16x8 af = *(const bf16x8*)&As[ra*32 + ((quad ^ ((ra >> 1) & 3)) << 3)];
#pragma unroll
        for (int nt = 0; nt < 4; nt++) {
            int rb = nt*16 + l16;
            bf16x8 bfg = *(const bf16x8*)&Bs[rb*32 + ((quad ^ ((rb >> 1) & 3)) << 3)];
            acc[nt] = __builtin_amdgcn_mfma_f32_16x16x32_bf16(af, bfg, acc[nt], 0, 0, 0);
        }
        __syncthreads();
    }

#pragma unroll
    for (int nt = 0; nt < 4; nt++) {
        int n = n0 + nt*16 + l16;
        if (n >= XPROJ_N) continue;
#pragma unroll
        for (int rr = 0; rr < 4; rr++) {
            int m = m0 + wave*16 + quad*4 + rr;
            atomicAdd(&projf[(size_t)m * XPROJ_N + n], acc[nt][rr]);
        }
    }
}

// ---------------- dt_proj: 64x64 tile, K=48, A from fp32 proj ---------------
__global__ __launch_bounds__(256)
void gemm_dt(const float* __restrict__ projf, const bf16_t* __restrict__ B,
             bf16_t* __restrict__ C, const float* __restrict__ bias) {
    __shared__ __align__(16) bf16_t As[64*32];
    __shared__ __align__(16) bf16_t Bs[64*32];
    const int tid = threadIdx.x;
    const int m0 = blockIdx.x * 64, n0 = blockIdx.y * 64;
    const int r  = tid >> 2, p8 = (tid & 3) << 3;
    const int q8 = (((tid & 3) ^ ((r >> 1) & 3)) << 3);
    const int wave = tid >> 6, lane = tid & 63;
    const int quad = lane >> 4, l16 = lane & 15;

    f32x4 acc[4] = {{0.f,0.f,0.f,0.f},{0.f,0.f,0.f,0.f},
                    {0.f,0.f,0.f,0.f},{0.f,0.f,0.f,0.f}};

    for (int k0 = 0; k0 < DT_RANK; k0 += 32) {
        int gk = k0 + q8;
        bf16x8 av = {};
        if (gk + 8 <= DT_RANK) {
            const float* ap = projf + (size_t)(m0 + r) * XPROJ_N + gk;
            float4 f0 = *(const float4*)ap;
            float4 f1 = *(const float4*)(ap + 4);
            av[0]=(bf16_t)f0.x; av[1]=(bf16_t)f0.y; av[2]=(bf16_t)f0.z; av[3]=(bf16_t)f0.w;
            av[4]=(bf16_t)f1.x; av[5]=(bf16_t)f1.y; av[6]=(bf16_t)f1.z; av[7]=(bf16_t)f1.w;
        }
        *(bf16x8*)&As[r*32 + p8] = av;
        uint4 vb = {0u,0u,0u,0u};
        if (gk + 8 <= DT_RANK)
            vb = *(const uint4*)(B + (size_t)(n0 + r) * DT_RANK + gk);
        *(uint4*)&Bs[r*32 + p8] = vb;

        __syncthreads();
        int ra = wave*16 + l16;
        bf16x8 af = *(const bf16x8*)&As[ra*32 + ((quad ^ ((ra >> 1) & 3)) << 3)];
#pragma unroll
        for (int nt = 0; nt < 4; nt++) {
            int rb = nt*16 + l16;
            bf16x8 bfg = *(const bf16x8*)&Bs[rb*32 + ((quad ^ ((rb >> 1) & 3)) << 3)];
            acc[nt] = __builtin_amdgcn_mfma_f32_16x16x32_bf16(af, bfg, acc[nt], 0, 0, 0);
        }
        __syncthreads();
    }

#pragma unroll
    for (int nt = 0; nt < 4; nt++) {
        int n = n0 + nt*16 + l16;
#pragma unroll
        for (int rr = 0; rr < 4; rr++) {
            int m = m0 + wave*16 + quad*4 + rr;
            float u = acc[nt][rr] + bias[n];
            float sp = (u > 20.f) ? u : log1pf(__expf(u));
            C[(size_t)m * D_INNER + n] = (bf16_t)sp;
        }
    }
}

// ---------------- causal depthwise conv(4) + SiLU, 8 ch/thread vectorized ---
__global__ __launch_bounds__(192)
void conv_silu_kernel(const bf16_t* __restrict__ xz,
                      const float* __restrict__ cw,
                      const float* __restrict__ cb,
                      bf16_t* __restrict__ xc) {
    const int t = blockIdx.x;
    const int l = t & (SEQ - 1);
    const int d = threadIdx.x * 8;       // 192*8 = 1536

    float cwf[32];
#pragma unroll
    for (int q = 0; q < 8; q++)
        *(float4*)&cwf[q*4] = *(const float4*)&cw[d*4 + q*4];

    float acc[8];
    {
        float4 c0 = *(const float4*)&cb[d];
        float4 c1 = *(const float4*)&cb[d+4];
        acc[0]=c0.x; acc[1]=c0.y; acc[2]=c0.z; acc[3]=c0.w;
        acc[4]=c1.x; acc[5]=c1.y; acc[6]=c1.z; acc[7]=c1.w;
    }
#pragma unroll
    for (int k = 0; k < 4; k++) {
        if (l - 3 + k >= 0) {
            bf16x8 v = *(const bf16x8*)&xz[(size_t)(t - 3 + k) * (2*D_INNER) + d];
#pragma unroll
            for (int i = 0; i < 8; i++)
                acc[i] += (float)v[i] * cwf[i*4 + k];
        }
    }
    bf16x8 o;
#pragma unroll
    for (int i = 0; i < 8; i++) {
        float s = acc[i] / (1.f + __expf(-acc[i]));
        o[i] = (bf16_t)s;
    }
    *(bf16x8*)&xc[(size_t)t * D_INNER + d] = o;
}

// ---------------- chunked selective scan, 16 states/thread (3 kernels) ------
__global__ __launch_bounds__(256)
void scan_part1(const bf16_t* __restrict__ delta,
                const bf16_t* __restrict__ xc,
                const float* __restrict__ projf,
                const float* __restrict__ A_log,
                float* __restrict__ chunk_h, float* __restrict__ chunk_P) {
    const int tid = threadIdx.x;
    const int d = blockIdx.x * 256 + tid;
    const int c = blockIdx.y;
    const int b = blockIdx.z;
    __shared__ float Bs[LC][D_STATE];
    for (int i = tid; i < LC*D_STATE; i += 256) {
        int l = i >> 4, n = i & 15;
        size_t t = (size_t)b*SEQ + (size_t)c*LC + l;
        Bs[l][n] = projf[t*XPROJ_N + DT_RANK + n];
    }
    __syncthreads();
    float Av2[D_STATE];
#pragma unroll
    for (int n = 0; n < D_STATE; n++)
        Av2[n] = -__expf(A_log[d*D_STATE + n]) * 1.44269504f;   // A[n]*log2(e)
    float s[D_STATE];
#pragma unroll
    for (int n = 0; n < D_STATE; n++) s[n] = 0.f;
    float sdv = 0.f;
    const size_t tbase = (size_t)b*SEQ + (size_t)c*LC;
    for (int l = 0; l < LC; l++) {
        size_t t = tbase + l;
        float dv  = (float)delta[t*D_INNER + d];
        float xcv = (float)xc[t*D_INNER + d];
        float dx = dv * xcv;
        sdv += dv;
#pragma unroll
        for (int n = 0; n < D_STATE; n++) {
            float a = __builtin_amdgcn_exp2f(dv * Av2[n]);
            s[n] = a * s[n] + dx * Bs[l][n];
        }
    }
    size_t base = (((size_t)b*NCHUNK + c)*D_INNER + d)*D_STATE;
#pragma unroll
    for (int n = 0; n < D_STATE; n++) {
        chunk_h[base + n] = s[n];
        chunk_P[base + n] = __builtin_amdgcn_exp2f(Av2[n] * sdv);  // = prod a
    }
}

__global__ __launch_bounds__(256)
void scan_part2(float* __restrict__ chunk_h, const float* __restrict__ chunk_P) {
    int gid = blockIdx.x * 256 + threadIdx.x;      // b*(Di*N) + d*N + n
    int b  = gid / (D_INNER * D_STATE);
    int dn = gid - b * (D_INNER * D_STATE);
    float H = 0.f;
    for (int c = 0; c < NCHUNK; c++) {
        size_t idx = ((size_t)b*NCHUNK + c)*D_INNER*D_STATE + dn;
        float S = chunk_h[idx];
        float P = chunk_P[idx];
        chunk_h[idx] = H;          // becomes the initial state for chunk c
        H = P * H + S;
    }
}

__global__ __launch_bounds__(256)
void scan_part3(const bf16_t* __restrict__ delta,
                const bf16_t* __restrict__ xc,
                const float* __restrict__ projf,
                const bf16_t* __restrict__ xz,
                const float* __restrict__ A_log,
                const float* __restrict__ Dw,
                const float* __restrict__ chunk_h,
                bf16_t* __restrict__ y) {
    const int tid = threadIdx.x;
    const int d = blockIdx.x * 256 + tid;
    const int c = blockIdx.y;
    const int b = blockIdx.z;
    __shared__ float Bs[LC][D_STATE];
    __shared__ float Cs[LC][D_STATE];
    for (int i = tid; i < LC*D_STATE; i += 256) {
        int l = i >> 4, n = i & 15;
        size_t t = (size_t)b*SEQ + (size_t)c*LC + l;
        Bs[l][n] = projf[t*XPROJ_N + DT_RANK + n];
        Cs[l][n] = projf[t*XPROJ_N + DT_RANK + D_STATE + n];
    }
    __syncthreads();
    float Av2[D_STATE];
#pragma unroll
    for (int n = 0; n < D_STATE; n++)
        Av2[n] = -__expf(A_log[d*D_STATE + n]) * 1.44269504f;
    const float Dv = Dw[d];
    float s[D_STATE];
    size_t base = (((size_t)b*NCHUNK + c)*D_INNER + d)*D_STATE;
#pragma unroll
    for (int n = 0; n < D_STATE; n++) s[n] = chunk_h[base + n];
    const size_t tbase = (size_t)b*SEQ + (size_t)c*LC;
    for (int l = 0; l < LC; l++) {
        size_t t = tbase + l;
        float dv  = (float)delta[t*D_INNER + d];
        float xcv = (float)xc[t*D_INNER + d];
        float dx = dv * xcv;
        float acc = 0.f;
#pragma unroll
        for (int n = 0; n < D_STATE; n++) {
            float a = __builtin_amdgcn_exp2f(dv * Av2[n]);
            s[n] = a * s[n] + dx * Bs[l][n];
            acc += s[n] * Cs[l][n];
        }
        float zf = (float)xz[t*(2*D_INNER) + D_INNER + d];
        float g = zf / (1.f + __expf(-zf));
        y[t*D_INNER + d] = (bf16_t)((acc + xcv * Dv) * g);
    }
}

extern "C" void kernel_launch(void* const* d_in, const int* in_sizes, int n_in,
                              void* d_out, int out_size, void* d_ws, size_t ws_size,
                              hipStream_t stream) {
    const float* x          = (const float*)d_in[0];
    const float* norm_w     = (const float*)d_in[1];
    const float* in_proj_w  = (const float*)d_in[2];
    const float* conv_w     = (const float*)d_in[3];
    const float* conv_b     = (const float*)d_in[4];
    const float* x_proj_w   = (const float*)d_in[5];
    const float* dt_proj_w  = (const float*)d_in[6];
    const float* dt_proj_b  = (const float*)d_in[7];
    const float* A_log      = (const float*)d_in[8];
    const float* Dw         = (const float*)d_in[9];
    const float* out_proj_w = (const float*)d_in[10];

    float* out0 = (float*)d_out;                       // x + out_proj(y)
    float* out1 = out0 + (size_t)NTOK * D_MODEL;       // residual copy

    const size_t n_chunkst = (size_t)NB*NCHUNK*D_INNER*D_STATE;

    char* ws = (char*)d_ws;
    bf16_t* w_in  = (bf16_t*)ws;  ws += (size_t)N_INW * sizeof(bf16_t);
    bf16_t* w_xp  = (bf16_t*)ws;  ws += (size_t)N_XPW * sizeof(bf16_t);
    bf16_t* w_dt  = (bf16_t*)ws;  ws += (size_t)N_DTW * sizeof(bf16_t);
    bf16_t* w_op  = (bf16_t*)ws;  ws += (size_t)N_OPW * sizeof(bf16_t);
    bf16_t* h     = (bf16_t*)ws;  ws += (size_t)NTOK * D_MODEL   * sizeof(bf16_t);
    bf16_t* xz    = (bf16_t*)ws;  ws += (size_t)NTOK * 2*D_INNER * sizeof(bf16_t);
    bf16_t* xc    = (bf16_t*)ws;  ws += (size_t)NTOK * D_INNER   * sizeof(bf16_t);
    float*  projf = (float*)ws;   ws += (size_t)NTOK * XPROJ_N   * sizeof(float);
    bf16_t* delta = (bf16_t*)ws;  ws += (size_t)NTOK * D_INNER   * sizeof(bf16_t);
    bf16_t* y     = (bf16_t*)ws;  ws += (size_t)NTOK * D_INNER   * sizeof(bf16_t);
    float*  ch    = (float*)ws;   ws += n_chunkst * sizeof(float);
    float*  cP    = (float*)ws;   ws += n_chunkst * sizeof(float);

    // 0+1) weight cvt + RMSNorm + proj_f32 zero, one launch
    prep_kernel<<<CVT_BLOCKS + NTOK + ZERO_BLOCKS, 256, 0, stream>>>(
        in_proj_w, w_in, x_proj_w, w_xp, dt_proj_w, w_dt, out_proj_w, w_op,
        x, norm_w, h, projf);
    // 2) in_proj (dbuf 128-tile)
    gemm_nt128<<<dim3(NTOK/128, (2*D_INNER)/128), 256, 0, stream>>>(
        h, D_MODEL, w_in, D_MODEL, xz, 2*D_INNER, D_MODEL);
    // 3) conv + SiLU
    conv_silu_kernel<<<NTOK, 192, 0, stream>>>(xz, conv_w, conv_b, xc);
    // 4) x_proj split-K x4, atomic fp32 accumulate into projf
    gemm_xp<<<dim3(NTOK/64, 2, XP_KS), 256, 0, stream>>>(xc, w_xp, projf);
    // 5) dt_proj + softplus (A staged from fp32 projf)
    gemm_dt<<<dim3(NTOK/64, D_INNER/64), 256, 0, stream>>>(projf, w_dt, delta, dt_proj_b);
    // 6) chunked selective scan (3 kernels, no per-thread LC-array)
    scan_part1<<<dim3(D_INNER/256, NCHUNK, NB), 256, 0, stream>>>(
        delta, xc, projf, A_log, ch, cP);
    scan_part2<<<(int)((size_t)NB*D_INNER*D_STATE/256), 256, 0, stream>>>(ch, cP);
    scan_part3<<<dim3(D_INNER/256, NCHUNK, NB), 256, 0, stream>>>(
        delta, xc, projf, xz, A_log, Dw, ch, y);
    // 7) out_proj 128x64 dbuf + residual epilogue
    gemm_op<<<dim3(NTOK/128, D_MODEL/64), 256, 0, stream>>>(
        y, w_op, out0, x, out1);
}